// Round 11
// baseline (82.191 us; speedup 1.0000x reference)
//
#include <hip/hip_runtime.h>
#include <math.h>

// Problem constants (reference: B,D,E,H = 4,128,512,512)
#define BATCH 4
#define DDIM  128
#define EDIM  512
#define HDIM  512

// c = 2*log2(e): P=exp2(c*dec_t), Q=exp2(c*enc_t) so e^{2(dec+enc)} = P*Q
#define TANH_SCALE 2.8853900817779268f

typedef short short8v __attribute__((ext_vector_type(8)));
typedef float f32x4   __attribute__((ext_vector_type(4)));

#define EXP2F(x) __builtin_amdgcn_exp2f(x)
#define RCPF(x)  __builtin_amdgcn_rcpf(x)

// fp32 -> bf16 bits, round-to-nearest-even
static __device__ inline unsigned short f2bf(float f) {
    unsigned u = __float_as_uint(f);
    return (unsigned short)((u + 0x7FFFu + ((u >> 16) & 1u)) >> 16);
}
// pack two fp32 -> one u32 {bf16(f1):bf16(f0)}
static __device__ inline unsigned pack_bf2(float f0, float f1) {
    unsigned u0 = __float_as_uint(f0), u1 = __float_as_uint(f1);
    u0 += 0x7FFFu + ((u0 >> 16) & 1u);
    u1 += 0x7FFFu + ((u1 >> 16) & 1u);
    return __builtin_amdgcn_perm(u1, u0, 0x07060302u);
}
// bf16 bits -> fp32
static __device__ inline float bf2f(unsigned short h) {
    return __uint_as_float(((unsigned)h) << 16);
}

// ---------------------------------------------------------------------------
// bf16 MFMA GEMM pair (NT), 2-phase pipeline — UNCHANGED from R10.
// ---------------------------------------------------------------------------
__global__ __launch_bounds__(256)
void gemm_both(const float* __restrict__ xdec, const float* __restrict__ W2,
               const float* __restrict__ xenc, const float* __restrict__ W1,
               unsigned short* __restrict__ P, unsigned short* __restrict__ Q) {
    __shared__ unsigned short As[2][64][40];   // 10 KB (dbuf, 80B rows)
    __shared__ unsigned short Bs[2][64][40];   // 10 KB

    const int id = blockIdx.x;
    const float *Ab, *Bb;
    unsigned short* Cb;
    int m0, n0;
    if (id < 64) {                 // dec: 4b x 2m(d) x 8n(h)
        int b = id >> 4, r = id & 15;
        m0 = (r >> 3) * 64; n0 = (r & 7) * 64;
        Ab = xdec + (long)b * DDIM * HDIM;
        Bb = W2;
        Cb = P + (long)b * DDIM * HDIM;
    } else {                       // enc: 4b x 8m(h) x 8n(e)
        int t2 = id - 64;
        int b = t2 >> 6, r = t2 & 63;
        m0 = (r >> 3) * 64; n0 = (r & 7) * 64;
        Ab = W1;
        Bb = xenc + (long)b * EDIM * HDIM;
        Cb = Q + (long)b * HDIM * EDIM;
    }

    const int t    = threadIdx.x;
    const int srow = t >> 2;            // 0..63: staged row
    const int skq  = (t & 3) << 3;      // 0,8,16,24: k-offset (8 elems)

    const int wid = t >> 6, wm = wid >> 1, wn = wid & 1;
    const int l   = t & 63, lr = l & 15, c16 = l >> 4;

    f32x4 acc[2][2] = {};

    const float* ap = Ab + (long)(m0 + srow) * HDIM + skq;
    const float* bp = Bb + (long)(n0 + srow) * HDIM + skq;

    // prologue: load K-step 0
    float4 a0 = *(const float4*)ap, a1 = *(const float4*)(ap + 4);
    float4 b0 = *(const float4*)bp, b1 = *(const float4*)(bp + 4);

    int cur = 0;
    for (int k0 = 0; k0 < HDIM; k0 += 32) {
        uint4 apk, bpk;
        apk.x = pack_bf2(a0.x, a0.y); apk.y = pack_bf2(a0.z, a0.w);
        apk.z = pack_bf2(a1.x, a1.y); apk.w = pack_bf2(a1.z, a1.w);
        bpk.x = pack_bf2(b0.x, b0.y); bpk.y = pack_bf2(b0.z, b0.w);
        bpk.z = pack_bf2(b1.x, b1.y); bpk.w = pack_bf2(b1.z, b1.w);
        *(uint4*)&As[cur][srow][skq] = apk;
        *(uint4*)&Bs[cur][srow][skq] = bpk;

        if (k0 + 32 < HDIM) {
            ap += 32; bp += 32;
            a0 = *(const float4*)ap; a1 = *(const float4*)(ap + 4);
            b0 = *(const float4*)bp; b1 = *(const float4*)(bp + 4);
        }

        asm volatile("s_waitcnt lgkmcnt(0)" ::: "memory");
        __builtin_amdgcn_s_barrier();
        __builtin_amdgcn_sched_barrier(0);

        short8v af[2], bf[2];
        #pragma unroll
        for (int fm = 0; fm < 2; ++fm)
            af[fm] = *(const short8v*)&As[cur][wm * 32 + fm * 16 + lr][c16 * 8];
        #pragma unroll
        for (int fn = 0; fn < 2; ++fn)
            bf[fn] = *(const short8v*)&Bs[cur][wn * 32 + fn * 16 + lr][c16 * 8];
        #pragma unroll
        for (int fm = 0; fm < 2; ++fm)
            #pragma unroll
            for (int fn = 0; fn < 2; ++fn)
                acc[fm][fn] = __builtin_amdgcn_mfma_f32_16x16x32_bf16(
                    af[fm], bf[fn], acc[fm][fn], 0, 0, 0);
        cur ^= 1;
    }

    const int crow = c16 << 2;
    #pragma unroll
    for (int fm = 0; fm < 2; ++fm)
        #pragma unroll
        for (int fn = 0; fn < 2; ++fn)
            #pragma unroll
            for (int r = 0; r < 4; ++r) {
                int rr = m0 + wm * 32 + fm * 16 + crow + r;
                int cc = n0 + wn * 32 + fn * 16 + lr;
                Cb[(long)rr * 512 + cc] = f2bf(EXP2F(TANH_SCALE * acc[fm][fn][r]));
            }
}

// ---------------------------------------------------------------------------
// Kernel A — DIAGNOSTIC x4 REP variant of R10's attn_partial.
// Inner math identical to R10; the whole body repeats 4x with an
// opaque-zero accumulator re-init (asm keep-alive) so the compiler must
// recompute each rep. All global writes idempotent -> output identical,
// deterministic. Purpose: (1) dispatch duration ~4x so it rises above the
// harness fillBuffer rows in the profiler top-5 and exposes VALUBusy /
// Occupancy / LDS-conflict / FETCH for this kernel; (2) attn time =
// (total_R11 - total_R10) / 3.
// ---------------------------------------------------------------------------
__global__ __launch_bounds__(512)
void attn_partial(const unsigned short* __restrict__ P,  // (B,D,H) bf16 exp2
                  const unsigned short* __restrict__ Q,  // (B,H,E) bf16 exp2
                  const float* __restrict__ vw,          // (H)
                  float* __restrict__ partial) {
    const int g     = blockIdx.x;           // 0..1023
    const int xcd   = g & 7;
    const int b     = xcd & 3;
    const int idx   = g >> 3;               // 0..127
    const int chunk = idx & 3;              // 0..3
    const int dp    = (idx >> 2) + ((xcd >> 2) << 5);  // 0..63
    const int pair  = b * 64 + dp;          // 0..255
    const int bd0   = pair * 2;
    const int t     = threadIdx.x;          // 0..511
    const int eq    = t & 127;              // e-quad (4 e's each)
    const int hg    = t >> 7;               // h-subgroup 0..3 (32 h each)
    const int h0    = chunk * 128;

    __shared__ float4 combo[128];           // {P0, P1, -2v, pad} (2 KB)
    __shared__ float  lds[4][128][8];       // [hg][eq][d*4+ep]  (16 KB)

    if (t < 128) {
        int h = h0 + t;
        combo[t] = make_float4(bf2f(P[bd0 * HDIM + h]),
                               bf2f(P[(bd0 + 1) * HDIM + h]),
                               -2.0f * vw[h], 0.0f);
    }
    __syncthreads();

    const unsigned short* qb =
        Q + b * HDIM * EDIM + (h0 + hg * 32) * EDIM + eq * 4;
    float* pp = partial + ((size_t)pair * 4 + chunk) * 1024;

    for (int rep = 0; rep < 4; ++rep) {
        float zero = 0.0f;
        asm volatile("" : "+v"(zero));      // opaque: forces real recompute
        float a00 = zero, a01 = zero, a02 = zero, a03 = zero;
        float a10 = zero, a11 = zero, a12 = zero, a13 = zero;
        #pragma unroll 8
        for (int ii = 0; ii < 32; ++ii) {
            uint2  qv = *(const uint2*)(qb + (size_t)ii * EDIM);
            float4 c  = combo[hg * 32 + ii];
            float q0 = __uint_as_float(qv.x << 16);
            float q1 = __uint_as_float(qv.x & 0xffff0000u);
            float q2 = __uint_as_float(qv.y << 16);
            float q3 = __uint_as_float(qv.y & 0xffff0000u);
            a00 = fmaf(c.z, RCPF(fmaf(c.x, q0, 1.0f)), a00);
            a01 = fmaf(c.z, RCPF(fmaf(c.x, q1, 1.0f)), a01);
            a02 = fmaf(c.z, RCPF(fmaf(c.x, q2, 1.0f)), a02);
            a03 = fmaf(c.z, RCPF(fmaf(c.x, q3, 1.0f)), a03);
            a10 = fmaf(c.z, RCPF(fmaf(c.y, q0, 1.0f)), a10);
            a11 = fmaf(c.z, RCPF(fmaf(c.y, q1, 1.0f)), a11);
            a12 = fmaf(c.z, RCPF(fmaf(c.y, q2, 1.0f)), a12);
            a13 = fmaf(c.z, RCPF(fmaf(c.y, q3, 1.0f)), a13);
        }

        float* myl = &lds[hg][eq][0];
        myl[0] = a00; myl[1] = a01; myl[2] = a02; myl[3] = a03;
        myl[4] = a10; myl[5] = a11; myl[6] = a12; myl[7] = a13;
        __syncthreads();

        #pragma unroll
        for (int rp = 0; rp < 2; ++rp) {
            int pos = t + rp * 512;         // d*512 + e
            int d = pos >> 9, e = pos & 511;
            int j = d * 4 + (e & 3), eqi = e >> 2;
            float v = (lds[0][eqi][j] + lds[1][eqi][j]) +
                      (lds[2][eqi][j] + lds[3][eqi][j]);
            pp[pos] = v;
        }
        __syncthreads();                    // WAR: lds reused next rep
    }
}

// ---------------------------------------------------------------------------
// Kernel B: combine 4 partials + masked log_softmax — UNCHANGED from R10.
// ---------------------------------------------------------------------------
__global__ __launch_bounds__(512)
void lsm_final(const float* __restrict__ partial,
               const unsigned char* __restrict__ mask,  // (B,E)
               float* __restrict__ out) {               // (B,D,E)
    const int pair = blockIdx.x;       // 0..255 = b*64 + dp
    const int b    = pair >> 6;
    const int bd0  = pair * 2;
    const int e    = threadIdx.x;      // 0..511

    __shared__ float red0[8], red1[8];

    const float* pp = partial + (size_t)pair * 4096;
    float acc0 = (pp[e]        + pp[1024 + e]) + (pp[2048 + e] + pp[3072 + e]);
    float acc1 = (pp[512 + e]  + pp[1536 + e]) + (pp[2560 + e] + pp[3584 + e]);

    const bool mk = mask[b * EDIM + e];
    float val0 = mk ? -INFINITY : acc0;
    float val1 = mk ? -INFINITY : acc1;

    const int wid = e >> 6, lid = e & 63;

    float m0 = val0, m1 = val1;
    #pragma unroll
    for (int o = 32; o >= 1; o >>= 1) {
        m0 = fmaxf(m0, __shfl_xor(m0, o));
        m1 = fmaxf(m1, __shfl_xor(m1, o));
    }
    if (lid == 0) { red0[wid] = m0; red1[wid] = m1; }
    __syncthreads();
    m0 = red0[0]; m1 = red1[0];
    #pragma unroll
    for (int i = 1; i < 8; ++i) { m0 = fmaxf(m0, red0[i]); m1 = fmaxf(m1, red1[i]); }
    __syncthreads();

    float s0 = __expf(val0 - m0), s1 = __expf(val1 - m1);
    #pragma unroll
    for (int o = 32; o >= 1; o >>= 1) {
        s0 += __shfl_xor(s0, o);
        s1 += __shfl_xor(s1, o);
    }
    if (lid == 0) { red0[wid] = s0; red1[wid] = s1; }
    __syncthreads();
    float tot0 = 0.f, tot1 = 0.f;
    #pragma unroll
    for (int i = 0; i < 8; ++i) { tot0 += red0[i]; tot1 += red1[i]; }

    out[(long)bd0 * EDIM + e]       = val0 - m0 - __logf(tot0);
    out[(long)(bd0 + 1) * EDIM + e] = val1 - m1 - __logf(tot1);
}

// ---------------------------------------------------------------------------
extern "C" void kernel_launch(void* const* d_in, const int* in_sizes, int n_in,
                              void* d_out, int out_size, void* d_ws, size_t ws_size,
                              hipStream_t stream) {
    const float*         xdec = (const float*)d_in[0];         // (B,D,H)
    const float*         xenc = (const float*)d_in[1];         // (B,E,H)
    const unsigned char* mask = (const unsigned char*)d_in[2]; // (B,E)
    const float*         W1   = (const float*)d_in[3];         // (H,H)
    const float*         W2   = (const float*)d_in[4];         // (H,H)
    const float*         vw   = (const float*)d_in[5];         // (H)
    float*               out  = (float*)d_out;                 // (B,D,E)

    unsigned short* P = (unsigned short*)d_ws;                 // 262144 bf16 (512 KB)
    unsigned short* Q = P + 262144;                            // 1048576 bf16 (2 MB)
    float* partial    = (float*)(Q + 1048576);                 // 1048576 f32 (4 MB)

    gemm_both<<<320, 256, 0, stream>>>(xdec, W2, xenc, W1, P, Q);
    attn_partial<<<1024, 512, 0, stream>>>(P, Q, vw, partial);
    lsm_final<<<256, 512, 0, stream>>>(partial, mask, out);
}

// Round 12
// 33.770 us; speedup vs baseline: 2.4338x; 2.4338x over previous
//
#include <hip/hip_runtime.h>
#include <math.h>

// Problem constants (reference: B,D,E,H = 4,128,512,512)
#define BATCH 4
#define DDIM  128
#define EDIM  512
#define HDIM  512

// c = 2*log2(e): P=exp2(c*dec_t), Q=exp2(c*enc_t) so e^{2(dec+enc)} = P*Q
#define TANH_SCALE 2.8853900817779268f

typedef short short8v __attribute__((ext_vector_type(8)));
typedef float f32x4   __attribute__((ext_vector_type(4)));
typedef float f32x2   __attribute__((ext_vector_type(2)));

#define EXP2F(x) __builtin_amdgcn_exp2f(x)
#define RCPF(x)  __builtin_amdgcn_rcpf(x)

// fp32 -> bf16 bits, round-to-nearest-even
static __device__ inline unsigned short f2bf(float f) {
    unsigned u = __float_as_uint(f);
    return (unsigned short)((u + 0x7FFFu + ((u >> 16) & 1u)) >> 16);
}
// pack two fp32 -> one u32 {bf16(f1):bf16(f0)}
static __device__ inline unsigned pack_bf2(float f0, float f1) {
    unsigned u0 = __float_as_uint(f0), u1 = __float_as_uint(f1);
    u0 += 0x7FFFu + ((u0 >> 16) & 1u);
    u1 += 0x7FFFu + ((u1 >> 16) & 1u);
    return __builtin_amdgcn_perm(u1, u0, 0x07060302u);
}
// bf16 bits -> fp32
static __device__ inline float bf2f(unsigned short h) {
    return __uint_as_float(((unsigned)h) << 16);
}

// ---------------------------------------------------------------------------
// bf16 MFMA GEMM pair (NT), 2-phase pipeline — UNCHANGED from R10.
// ---------------------------------------------------------------------------
__global__ __launch_bounds__(256)
void gemm_both(const float* __restrict__ xdec, const float* __restrict__ W2,
               const float* __restrict__ xenc, const float* __restrict__ W1,
               unsigned short* __restrict__ P, unsigned short* __restrict__ Q) {
    __shared__ unsigned short As[2][64][40];   // 10 KB (dbuf, 80B rows)
    __shared__ unsigned short Bs[2][64][40];   // 10 KB

    const int id = blockIdx.x;
    const float *Ab, *Bb;
    unsigned short* Cb;
    int m0, n0;
    if (id < 64) {                 // dec: 4b x 2m(d) x 8n(h)
        int b = id >> 4, r = id & 15;
        m0 = (r >> 3) * 64; n0 = (r & 7) * 64;
        Ab = xdec + (long)b * DDIM * HDIM;
        Bb = W2;
        Cb = P + (long)b * DDIM * HDIM;
    } else {                       // enc: 4b x 8m(h) x 8n(e)
        int t2 = id - 64;
        int b = t2 >> 6, r = t2 & 63;
        m0 = (r >> 3) * 64; n0 = (r & 7) * 64;
        Ab = W1;
        Bb = xenc + (long)b * EDIM * HDIM;
        Cb = Q + (long)b * HDIM * EDIM;
    }

    const int t    = threadIdx.x;
    const int srow = t >> 2;            // 0..63: staged row
    const int skq  = (t & 3) << 3;      // 0,8,16,24: k-offset (8 elems)

    const int wid = t >> 6, wm = wid >> 1, wn = wid & 1;
    const int l   = t & 63, lr = l & 15, c16 = l >> 4;

    f32x4 acc[2][2] = {};

    const float* ap = Ab + (long)(m0 + srow) * HDIM + skq;
    const float* bp = Bb + (long)(n0 + srow) * HDIM + skq;

    // prologue: load K-step 0
    float4 a0 = *(const float4*)ap, a1 = *(const float4*)(ap + 4);
    float4 b0 = *(const float4*)bp, b1 = *(const float4*)(bp + 4);

    int cur = 0;
    for (int k0 = 0; k0 < HDIM; k0 += 32) {
        uint4 apk, bpk;
        apk.x = pack_bf2(a0.x, a0.y); apk.y = pack_bf2(a0.z, a0.w);
        apk.z = pack_bf2(a1.x, a1.y); apk.w = pack_bf2(a1.z, a1.w);
        bpk.x = pack_bf2(b0.x, b0.y); bpk.y = pack_bf2(b0.z, b0.w);
        bpk.z = pack_bf2(b1.x, b1.y); bpk.w = pack_bf2(b1.z, b1.w);
        *(uint4*)&As[cur][srow][skq] = apk;
        *(uint4*)&Bs[cur][srow][skq] = bpk;

        if (k0 + 32 < HDIM) {
            ap += 32; bp += 32;
            a0 = *(const float4*)ap; a1 = *(const float4*)(ap + 4);
            b0 = *(const float4*)bp; b1 = *(const float4*)(bp + 4);
        }

        asm volatile("s_waitcnt lgkmcnt(0)" ::: "memory");
        __builtin_amdgcn_s_barrier();
        __builtin_amdgcn_sched_barrier(0);

        short8v af[2], bf[2];
        #pragma unroll
        for (int fm = 0; fm < 2; ++fm)
            af[fm] = *(const short8v*)&As[cur][wm * 32 + fm * 16 + lr][c16 * 8];
        #pragma unroll
        for (int fn = 0; fn < 2; ++fn)
            bf[fn] = *(const short8v*)&Bs[cur][wn * 32 + fn * 16 + lr][c16 * 8];
        #pragma unroll
        for (int fm = 0; fm < 2; ++fm)
            #pragma unroll
            for (int fn = 0; fn < 2; ++fn)
                acc[fm][fn] = __builtin_amdgcn_mfma_f32_16x16x32_bf16(
                    af[fm], bf[fn], acc[fm][fn], 0, 0, 0);
        cur ^= 1;
    }

    const int crow = c16 << 2;
    #pragma unroll
    for (int fm = 0; fm < 2; ++fm)
        #pragma unroll
        for (int fn = 0; fn < 2; ++fn)
            #pragma unroll
            for (int r = 0; r < 4; ++r) {
                int rr = m0 + wm * 32 + fm * 16 + crow + r;
                int cc = n0 + wn * 32 + fn * 16 + lr;
                Cb[(long)rr * 512 + cc] = f2bf(EXP2F(TANH_SCALE * acc[fm][fn][r]));
            }
}

// ---------------------------------------------------------------------------
// Kernel A (v3): partial tanh-dot, 2h PAIR-COMBINE + v_pk packed math.
//   a/(1+P q0) + b/(1+P q1)  ->  (a*y' + b*x') * rcp(x'*y')
// halves the 8-cycle v_rcp ops; v_pk_fma/mul (broadcast via op_sel) halves
// full-rate issue. Reduce LDS padded to 9 floats (conflict-free).
// Grid unchanged: 1024 blocks = 256 pairs x 4 h-chunks; 512 thr =
// 128 e-quads x 4 h-subgroups; partial layout unchanged.
// ---------------------------------------------------------------------------
__global__ __launch_bounds__(512)
void attn_partial(const unsigned short* __restrict__ P,  // (B,D,H) bf16 exp2
                  const unsigned short* __restrict__ Q,  // (B,H,E) bf16 exp2
                  const float* __restrict__ vw,          // (H)
                  float* __restrict__ partial) {
    const int g     = blockIdx.x;           // 0..1023
    const int xcd   = g & 7;
    const int b     = xcd & 3;
    const int idx   = g >> 3;               // 0..127
    const int chunk = idx & 3;              // 0..3
    const int dp    = (idx >> 2) + ((xcd >> 2) << 5);  // 0..63
    const int pair  = b * 64 + dp;          // 0..255
    const int bd0   = pair * 2;
    const int t     = threadIdx.x;          // 0..511
    const int eq    = t & 127;              // e-quad (4 e's each)
    const int hg    = t >> 7;               // h-subgroup 0..3 (32 h each)
    const int h0    = chunk * 128;

    __shared__ f32x2 combo2[64][3];         // per h-pair: {P0pr, P1pr, (a,b)}
    __shared__ float lds[4][128][9];        // padded: conflict-free reduce

    if (t < 64) {
        int h = h0 + t * 2;
        f32x2 p0, p1, vv;
        p0.x = bf2f(P[bd0 * HDIM + h]);       p0.y = bf2f(P[bd0 * HDIM + h + 1]);
        p1.x = bf2f(P[(bd0 + 1) * HDIM + h]); p1.y = bf2f(P[(bd0 + 1) * HDIM + h + 1]);
        vv.x = -2.0f * vw[h];                 vv.y = -2.0f * vw[h + 1];
        combo2[t][0] = p0; combo2[t][1] = p1; combo2[t][2] = vv;
    }
    __syncthreads();

    const unsigned short* qb =
        Q + b * HDIM * EDIM + (h0 + hg * 32) * EDIM + eq * 4;
    float a00 = 0.f, a01 = 0.f, a02 = 0.f, a03 = 0.f;
    float a10 = 0.f, a11 = 0.f, a12 = 0.f, a13 = 0.f;
    f32x2 ones; ones.x = 1.0f; ones.y = 1.0f;

    // one "set": e-pair x d-row x (h0,h1) -> 5 pk + 2 rcp + 2 fma
#define PAIR_SET(Pp, q0p, q1p, VV, accA, accB)                                  \
    {                                                                           \
        f32x2 xp, yp, den, tt, num;                                             \
        asm("v_pk_fma_f32 %0, %1, %2, %3 op_sel_hi:[0,1,1]"                     \
            : "=v"(xp) : "v"(Pp), "v"(q0p), "v"(ones));                         \
        asm("v_pk_fma_f32 %0, %1, %2, %3 op_sel:[1,0,0] op_sel_hi:[1,1,1]"      \
            : "=v"(yp) : "v"(Pp), "v"(q1p), "v"(ones));                         \
        asm("v_pk_mul_f32 %0, %1, %2" : "=v"(den) : "v"(xp), "v"(yp));          \
        asm("v_pk_mul_f32 %0, %1, %2 op_sel:[1,0] op_sel_hi:[1,1]"              \
            : "=v"(tt) : "v"(VV), "v"(xp));                                     \
        asm("v_pk_fma_f32 %0, %1, %2, %3 op_sel_hi:[0,1,1]"                     \
            : "=v"(num) : "v"(VV), "v"(yp), "v"(tt));                           \
        accA = fmaf(num.x, RCPF(den.x), accA);                                  \
        accB = fmaf(num.y, RCPF(den.y), accB);                                  \
    }

    #pragma unroll 4
    for (int ii = 0; ii < 16; ++ii) {       // 16 h-pairs = 32 h
        uint2 qv0 = *(const uint2*)(qb + (size_t)(2 * ii) * EDIM);
        uint2 qv1 = *(const uint2*)(qb + (size_t)(2 * ii + 1) * EDIM);
        f32x2 P0 = combo2[hg * 16 + ii][0];
        f32x2 P1 = combo2[hg * 16 + ii][1];
        f32x2 VV = combo2[hg * 16 + ii][2];
        f32x2 qA0, qB0, qA1, qB1;           // (e0,e1) and (e2,e3) per h
        qA0.x = __uint_as_float(qv0.x << 16);
        qA0.y = __uint_as_float(qv0.x & 0xffff0000u);
        qB0.x = __uint_as_float(qv0.y << 16);
        qB0.y = __uint_as_float(qv0.y & 0xffff0000u);
        qA1.x = __uint_as_float(qv1.x << 16);
        qA1.y = __uint_as_float(qv1.x & 0xffff0000u);
        qB1.x = __uint_as_float(qv1.y << 16);
        qB1.y = __uint_as_float(qv1.y & 0xffff0000u);

        PAIR_SET(P0, qA0, qA1, VV, a00, a01);
        PAIR_SET(P0, qB0, qB1, VV, a02, a03);
        PAIR_SET(P1, qA0, qA1, VV, a10, a11);
        PAIR_SET(P1, qB0, qB1, VV, a12, a13);
    }
#undef PAIR_SET

    float* myl = &lds[hg][eq][0];
    myl[0] = a00; myl[1] = a01; myl[2] = a02; myl[3] = a03;
    myl[4] = a10; myl[5] = a11; myl[6] = a12; myl[7] = a13;
    __syncthreads();

    // cross-subgroup reduce + write: thread t covers out positions t, t+512
    float* pp = partial + ((size_t)pair * 4 + chunk) * 1024;
    #pragma unroll
    for (int rp = 0; rp < 2; ++rp) {
        int pos = t + rp * 512;             // d*512 + e
        int d = pos >> 9, e = pos & 511;
        int j = d * 4 + (e & 3), eqi = e >> 2;
        float v = (lds[0][eqi][j] + lds[1][eqi][j]) +
                  (lds[2][eqi][j] + lds[3][eqi][j]);
        pp[pos] = v;
    }
}

// ---------------------------------------------------------------------------
// Kernel B: combine 4 partials + masked log_softmax — UNCHANGED from R10.
// ---------------------------------------------------------------------------
__global__ __launch_bounds__(512)
void lsm_final(const float* __restrict__ partial,
               const unsigned char* __restrict__ mask,  // (B,E)
               float* __restrict__ out) {               // (B,D,E)
    const int pair = blockIdx.x;       // 0..255 = b*64 + dp
    const int b    = pair >> 6;
    const int bd0  = pair * 2;
    const int e    = threadIdx.x;      // 0..511

    __shared__ float red0[8], red1[8];

    const float* pp = partial + (size_t)pair * 4096;
    float acc0 = (pp[e]        + pp[1024 + e]) + (pp[2048 + e] + pp[3072 + e]);
    float acc1 = (pp[512 + e]  + pp[1536 + e]) + (pp[2560 + e] + pp[3584 + e]);

    const bool mk = mask[b * EDIM + e];
    float val0 = mk ? -INFINITY : acc0;
    float val1 = mk ? -INFINITY : acc1;

    const int wid = e >> 6, lid = e & 63;

    float m0 = val0, m1 = val1;
    #pragma unroll
    for (int o = 32; o >= 1; o >>= 1) {
        m0 = fmaxf(m0, __shfl_xor(m0, o));
        m1 = fmaxf(m1, __shfl_xor(m1, o));
    }
    if (lid == 0) { red0[wid] = m0; red1[wid] = m1; }
    __syncthreads();
    m0 = red0[0]; m1 = red1[0];
    #pragma unroll
    for (int i = 1; i < 8; ++i) { m0 = fmaxf(m0, red0[i]); m1 = fmaxf(m1, red1[i]); }
    __syncthreads();

    float s0 = __expf(val0 - m0), s1 = __expf(val1 - m1);
    #pragma unroll
    for (int o = 32; o >= 1; o >>= 1) {
        s0 += __shfl_xor(s0, o);
        s1 += __shfl_xor(s1, o);
    }
    if (lid == 0) { red0[wid] = s0; red1[wid] = s1; }
    __syncthreads();
    float tot0 = 0.f, tot1 = 0.f;
    #pragma unroll
    for (int i = 0; i < 8; ++i) { tot0 += red0[i]; tot1 += red1[i]; }

    out[(long)bd0 * EDIM + e]       = val0 - m0 - __logf(tot0);
    out[(long)(bd0 + 1) * EDIM + e] = val1 - m1 - __logf(tot1);
}

// ---------------------------------------------------------------------------
extern "C" void kernel_launch(void* const* d_in, const int* in_sizes, int n_in,
                              void* d_out, int out_size, void* d_ws, size_t ws_size,
                              hipStream_t stream) {
    const float*         xdec = (const float*)d_in[0];         // (B,D,H)
    const float*         xenc = (const float*)d_in[1];         // (B,E,H)
    const unsigned char* mask = (const unsigned char*)d_in[2]; // (B,E)
    const float*         W1   = (const float*)d_in[3];         // (H,H)
    const float*         W2   = (const float*)d_in[4];         // (H,H)
    const float*         vw   = (const float*)d_in[5];         // (H)
    float*               out  = (float*)d_out;                 // (B,D,E)

    unsigned short* P = (unsigned short*)d_ws;                 // 262144 bf16 (512 KB)
    unsigned short* Q = P + 262144;                            // 1048576 bf16 (2 MB)
    float* partial    = (float*)(Q + 1048576);                 // 1048576 f32 (4 MB)

    gemm_both<<<320, 256, 0, stream>>>(xdec, W2, xenc, W1, P, Q);
    attn_partial<<<1024, 512, 0, stream>>>(P, Q, vw, partial);
    lsm_final<<<256, 512, 0, stream>>>(partial, mask, out);
}

// Round 13
// 30.714 us; speedup vs baseline: 2.6760x; 1.0995x over previous
//
#include <hip/hip_runtime.h>
#include <math.h>

// Problem constants (reference: B,D,E,H = 4,128,512,512)
#define BATCH 4
#define DDIM  128
#define EDIM  512
#define HDIM  512

// c = 2*log2(e): P=exp2(c*dec_t), Q=exp2(c*enc_t) so e^{2(dec+enc)} = P*Q
#define TANH_SCALE 2.8853900817779268f

typedef short short8v __attribute__((ext_vector_type(8)));
typedef float f32x4   __attribute__((ext_vector_type(4)));
typedef float f32x2   __attribute__((ext_vector_type(2)));

#define EXP2F(x) __builtin_amdgcn_exp2f(x)
#define RCPF(x)  __builtin_amdgcn_rcpf(x)

// fp32 -> bf16 bits, round-to-nearest-even
static __device__ inline unsigned short f2bf(float f) {
    unsigned u = __float_as_uint(f);
    return (unsigned short)((u + 0x7FFFu + ((u >> 16) & 1u)) >> 16);
}
// pack two fp32 -> one u32 {bf16(f1):bf16(f0)}
static __device__ inline unsigned pack_bf2(float f0, float f1) {
    unsigned u0 = __float_as_uint(f0), u1 = __float_as_uint(f1);
    u0 += 0x7FFFu + ((u0 >> 16) & 1u);
    u1 += 0x7FFFu + ((u1 >> 16) & 1u);
    return __builtin_amdgcn_perm(u1, u0, 0x07060302u);
}
// bf16 bits -> fp32
static __device__ inline float bf2f(unsigned short h) {
    return __uint_as_float(((unsigned)h) << 16);
}

// ---------------------------------------------------------------------------
// bf16 MFMA GEMM pair (NT), 2-phase pipeline — UNCHANGED from R10/R12.
//   blocks 0..63   : P[b,d,h] = exp2(c * sum_k xdec[b,d,k]*W2[h,k])
//   blocks 64..319 : Q[b,h,e] = exp2(c * sum_k W1[h,k]*xenc[b,e,k])
// ---------------------------------------------------------------------------
__global__ __launch_bounds__(256)
void gemm_both(const float* __restrict__ xdec, const float* __restrict__ W2,
               const float* __restrict__ xenc, const float* __restrict__ W1,
               unsigned short* __restrict__ P, unsigned short* __restrict__ Q) {
    __shared__ unsigned short As[2][64][40];   // 10 KB (dbuf, 80B rows)
    __shared__ unsigned short Bs[2][64][40];   // 10 KB

    const int id = blockIdx.x;
    const float *Ab, *Bb;
    unsigned short* Cb;
    int m0, n0;
    if (id < 64) {                 // dec: 4b x 2m(d) x 8n(h)
        int b = id >> 4, r = id & 15;
        m0 = (r >> 3) * 64; n0 = (r & 7) * 64;
        Ab = xdec + (long)b * DDIM * HDIM;
        Bb = W2;
        Cb = P + (long)b * DDIM * HDIM;
    } else {                       // enc: 4b x 8m(h) x 8n(e)
        int t2 = id - 64;
        int b = t2 >> 6, r = t2 & 63;
        m0 = (r >> 3) * 64; n0 = (r & 7) * 64;
        Ab = W1;
        Bb = xenc + (long)b * EDIM * HDIM;
        Cb = Q + (long)b * HDIM * EDIM;
    }

    const int t    = threadIdx.x;
    const int srow = t >> 2;            // 0..63: staged row
    const int skq  = (t & 3) << 3;      // 0,8,16,24: k-offset (8 elems)

    const int wid = t >> 6, wm = wid >> 1, wn = wid & 1;
    const int l   = t & 63, lr = l & 15, c16 = l >> 4;

    f32x4 acc[2][2] = {};

    const float* ap = Ab + (long)(m0 + srow) * HDIM + skq;
    const float* bp = Bb + (long)(n0 + srow) * HDIM + skq;

    // prologue: load K-step 0
    float4 a0 = *(const float4*)ap, a1 = *(const float4*)(ap + 4);
    float4 b0 = *(const float4*)bp, b1 = *(const float4*)(bp + 4);

    int cur = 0;
    for (int k0 = 0; k0 < HDIM; k0 += 32) {
        uint4 apk, bpk;
        apk.x = pack_bf2(a0.x, a0.y); apk.y = pack_bf2(a0.z, a0.w);
        apk.z = pack_bf2(a1.x, a1.y); apk.w = pack_bf2(a1.z, a1.w);
        bpk.x = pack_bf2(b0.x, b0.y); bpk.y = pack_bf2(b0.z, b0.w);
        bpk.z = pack_bf2(b1.x, b1.y); bpk.w = pack_bf2(b1.z, b1.w);
        *(uint4*)&As[cur][srow][skq] = apk;
        *(uint4*)&Bs[cur][srow][skq] = bpk;

        if (k0 + 32 < HDIM) {
            ap += 32; bp += 32;
            a0 = *(const float4*)ap; a1 = *(const float4*)(ap + 4);
            b0 = *(const float4*)bp; b1 = *(const float4*)(bp + 4);
        }

        asm volatile("s_waitcnt lgkmcnt(0)" ::: "memory");
        __builtin_amdgcn_s_barrier();
        __builtin_amdgcn_sched_barrier(0);

        short8v af[2], bf[2];
        #pragma unroll
        for (int fm = 0; fm < 2; ++fm)
            af[fm] = *(const short8v*)&As[cur][wm * 32 + fm * 16 + lr][c16 * 8];
        #pragma unroll
        for (int fn = 0; fn < 2; ++fn)
            bf[fn] = *(const short8v*)&Bs[cur][wn * 32 + fn * 16 + lr][c16 * 8];
        #pragma unroll
        for (int fm = 0; fm < 2; ++fm)
            #pragma unroll
            for (int fn = 0; fn < 2; ++fn)
                acc[fm][fn] = __builtin_amdgcn_mfma_f32_16x16x32_bf16(
                    af[fm], bf[fn], acc[fm][fn], 0, 0, 0);
        cur ^= 1;
    }

    const int crow = c16 << 2;
    #pragma unroll
    for (int fm = 0; fm < 2; ++fm)
        #pragma unroll
        for (int fn = 0; fn < 2; ++fn)
            #pragma unroll
            for (int r = 0; r < 4; ++r) {
                int rr = m0 + wm * 32 + fm * 16 + crow + r;
                int cc = n0 + wn * 32 + fn * 16 + lr;
                Cb[(long)rr * 512 + cc] = f2bf(EXP2F(TANH_SCALE * acc[fm][fn][r]));
            }
}

// ---------------------------------------------------------------------------
// MERGED attn + log_softmax. One block per (b, d-pair): 256 blocks = 1/CU
// (no tail), 1024 threads = 128 e-quads x 8 h-subgroups (64 h each) =
// 16 waves = 4 waves/SIMD. Inner math identical to R12 (2h pair-combine +
// v_pk packed). All 512 h in-block -> 8-way LDS reduce replaces the
// partial-buffer round-trip, and masked log_softmax runs in-block
// (waves 0-7 own d0, waves 8-15 own d1). Eliminates the lsm_final
// dispatch, its launch gap, and 8 MB of partial traffic.
// ---------------------------------------------------------------------------
__global__ __launch_bounds__(1024)
void attn_lsm(const unsigned short* __restrict__ P,    // (B,D,H) bf16 exp2
              const unsigned short* __restrict__ Q,    // (B,H,E) bf16 exp2
              const unsigned char* __restrict__ mask,  // (B,E)
              const float* __restrict__ vw,            // (H)
              float* __restrict__ out) {               // (B,D,E)
    const int g    = blockIdx.x;            // 0..255
    const int xcd  = g & 7;
    const int b    = xcd & 3;
    const int dp   = (g >> 3) + ((xcd >> 2) << 5);     // 0..63
    const int pair = b * 64 + dp;           // 0..255
    const int bd0  = pair * 2;
    const int t    = threadIdx.x;           // 0..1023
    const int eq   = t & 127;               // e-quad (4 e's each)
    const int hg   = t >> 7;                // h-subgroup 0..7 (64 h each)

    __shared__ f32x2 combo2[256][3];        // per h-pair: {P0pr, P1pr, (a,b)} 6KB
    __shared__ float lds[8][128][9];        // padded reduce buffer (36.9KB)
    __shared__ float red[16];

    if (t < 256) {
        int h = t * 2;
        f32x2 p0, p1, vv;
        p0.x = bf2f(P[bd0 * HDIM + h]);       p0.y = bf2f(P[bd0 * HDIM + h + 1]);
        p1.x = bf2f(P[(bd0 + 1) * HDIM + h]); p1.y = bf2f(P[(bd0 + 1) * HDIM + h + 1]);
        vv.x = -2.0f * vw[h];                 vv.y = -2.0f * vw[h + 1];
        combo2[t][0] = p0; combo2[t][1] = p1; combo2[t][2] = vv;
    }
    __syncthreads();

    const unsigned short* qb = Q + b * HDIM * EDIM + (hg * 64) * EDIM + eq * 4;
    float a00 = 0.f, a01 = 0.f, a02 = 0.f, a03 = 0.f;
    float a10 = 0.f, a11 = 0.f, a12 = 0.f, a13 = 0.f;
    f32x2 ones; ones.x = 1.0f; ones.y = 1.0f;

    // one "set": e-pair x d-row x (h0,h1) -> 5 pk + 2 rcp + 2 fma
#define PAIR_SET(Pp, q0p, q1p, VV, accA, accB)                                  \
    {                                                                           \
        f32x2 xp, yp, den, tt, num;                                             \
        asm("v_pk_fma_f32 %0, %1, %2, %3 op_sel_hi:[0,1,1]"                     \
            : "=v"(xp) : "v"(Pp), "v"(q0p), "v"(ones));                         \
        asm("v_pk_fma_f32 %0, %1, %2, %3 op_sel:[1,0,0] op_sel_hi:[1,1,1]"      \
            : "=v"(yp) : "v"(Pp), "v"(q1p), "v"(ones));                         \
        asm("v_pk_mul_f32 %0, %1, %2" : "=v"(den) : "v"(xp), "v"(yp));          \
        asm("v_pk_mul_f32 %0, %1, %2 op_sel:[1,0] op_sel_hi:[1,1]"              \
            : "=v"(tt) : "v"(VV), "v"(xp));                                     \
        asm("v_pk_fma_f32 %0, %1, %2, %3 op_sel_hi:[0,1,1]"                     \
            : "=v"(num) : "v"(VV), "v"(yp), "v"(tt));                           \
        accA = fmaf(num.x, RCPF(den.x), accA);                                  \
        accB = fmaf(num.y, RCPF(den.y), accB);                                  \
    }

    #pragma unroll 4
    for (int ii = 0; ii < 32; ++ii) {       // 32 h-pairs = 64 h
        uint2 qv0 = *(const uint2*)(qb + (size_t)(2 * ii) * EDIM);
        uint2 qv1 = *(const uint2*)(qb + (size_t)(2 * ii + 1) * EDIM);
        f32x2 P0 = combo2[hg * 32 + ii][0];
        f32x2 P1 = combo2[hg * 32 + ii][1];
        f32x2 VV = combo2[hg * 32 + ii][2];
        f32x2 qA0, qB0, qA1, qB1;           // (e0,e1) and (e2,e3) per h
        qA0.x = __uint_as_float(qv0.x << 16);
        qA0.y = __uint_as_float(qv0.x & 0xffff0000u);
        qB0.x = __uint_as_float(qv0.y << 16);
        qB0.y = __uint_as_float(qv0.y & 0xffff0000u);
        qA1.x = __uint_as_float(qv1.x << 16);
        qA1.y = __uint_as_float(qv1.x & 0xffff0000u);
        qB1.x = __uint_as_float(qv1.y << 16);
        qB1.y = __uint_as_float(qv1.y & 0xffff0000u);

        PAIR_SET(P0, qA0, qA1, VV, a00, a01);
        PAIR_SET(P0, qB0, qB1, VV, a02, a03);
        PAIR_SET(P1, qA0, qA1, VV, a10, a11);
        PAIR_SET(P1, qB0, qB1, VV, a12, a13);
    }
#undef PAIR_SET

    float* myl = &lds[hg][eq][0];
    myl[0] = a00; myl[1] = a01; myl[2] = a02; myl[3] = a03;
    myl[4] = a10; myl[5] = a11; myl[6] = a12; myl[7] = a13;
    __syncthreads();

    // cross-subgroup reduce: thread t owns output position t = d*512 + e
    const int d = t >> 9, e = t & 511;
    const int j = d * 4 + (e & 3), eqi = e >> 2;
    float acc = ((lds[0][eqi][j] + lds[1][eqi][j]) +
                 (lds[2][eqi][j] + lds[3][eqi][j])) +
                ((lds[4][eqi][j] + lds[5][eqi][j]) +
                 (lds[6][eqi][j] + lds[7][eqi][j]));

    const bool mk = mask[b * EDIM + e];
    float val = mk ? -INFINITY : acc;

    // --- masked log_softmax: waves 0..7 = d0, waves 8..15 = d1 ---
    const int wv = t >> 6, lid = t & 63, dg8 = d * 8;

    float m = val;
    #pragma unroll
    for (int o = 32; o >= 1; o >>= 1) m = fmaxf(m, __shfl_xor(m, o));
    if (lid == 0) red[wv] = m;
    __syncthreads();
    m = red[dg8];
    #pragma unroll
    for (int i = 1; i < 8; ++i) m = fmaxf(m, red[dg8 + i]);
    __syncthreads();                        // red reused

    float s = __expf(val - m);
    #pragma unroll
    for (int o = 32; o >= 1; o >>= 1) s += __shfl_xor(s, o);
    if (lid == 0) red[wv] = s;
    __syncthreads();
    float tot = 0.f;
    #pragma unroll
    for (int i = 0; i < 8; ++i) tot += red[dg8 + i];

    out[(long)(bd0 + d) * EDIM + e] = val - m - __logf(tot);
}

// ---------------------------------------------------------------------------
extern "C" void kernel_launch(void* const* d_in, const int* in_sizes, int n_in,
                              void* d_out, int out_size, void* d_ws, size_t ws_size,
                              hipStream_t stream) {
    const float*         xdec = (const float*)d_in[0];         // (B,D,H)
    const float*         xenc = (const float*)d_in[1];         // (B,E,H)
    const unsigned char* mask = (const unsigned char*)d_in[2]; // (B,E)
    const float*         W1   = (const float*)d_in[3];         // (H,H)
    const float*         W2   = (const float*)d_in[4];         // (H,H)
    const float*         vw   = (const float*)d_in[5];         // (H)
    float*               out  = (float*)d_out;                 // (B,D,E)

    unsigned short* P = (unsigned short*)d_ws;                 // 262144 bf16 (512 KB)
    unsigned short* Q = P + 262144;                            // 1048576 bf16 (2 MB)

    gemm_both<<<320, 256, 0, stream>>>(xdec, W2, xenc, W1, P, Q);
    attn_lsm<<<256, 1024, 0, stream>>>(P, Q, mask, vw, out);
}